// Round 6
// baseline (948.783 us; speedup 1.0000x reference)
//
#include <hip/hip_runtime.h>
#include <hip/hip_bf16.h>
#include <stdint.h>

#define NN 65536
#define DD 256

typedef uint32_t u32;
typedef __attribute__((ext_vector_type(4))) float f32x4;
typedef __attribute__((ext_vector_type(4))) u32 u32x4;
typedef __attribute__((ext_vector_type(2))) u32 u32x2;
typedef __attribute__((ext_vector_type(8))) short s16x8;

__device__ inline unsigned short f2bf(float f) {
    union { float f; u32 u; } v; v.f = f;
    u32 u = v.u;
    return (unsigned short)((u + 0x7fffu + ((u >> 16) & 1u)) >> 16);
}

__device__ inline void gl2lds16(const void* g, void* s) {
    __builtin_amdgcn_global_load_lds(
        (const __attribute__((address_space(1))) void*)g,
        (__attribute__((address_space(3))) void*)s, 16, 0, 0);
}

// ---- Pre-swizzled B image, 256-col tiles (R5-verified). Tile (ct,j,kk) = 32KB
// byte image of swizzled B LDS [256 cols][64 K] bf16; i==j block = bf16 identity.
__global__ void prep_w256(const float* __restrict__ W, unsigned short* __restrict__ Wimg) {
    int t = blockIdx.x * blockDim.x + threadIdx.x;
    int E = t * 4;
    int tile = E >> 14;
    int pin = E & 16383;
    int col = pin >> 6;
    int r2e = pin & 63;
    int ct = tile >> 4;
    int j = (tile >> 2) & 3;
    int kk = tile & 3;
    int kl = r2e ^ ((col & 7) << 3);
    int i = ct;
    int e = col;
    int f = kk * 64 + kl;
    u32 p0, p1;
    if (i == j) {
        unsigned short d0 = (e == f + 0) ? 0x3F80 : 0;
        unsigned short d1 = (e == f + 1) ? 0x3F80 : 0;
        unsigned short d2 = (e == f + 2) ? 0x3F80 : 0;
        unsigned short d3 = (e == f + 3) ? 0x3F80 : 0;
        p0 = (u32)d0 | ((u32)d1 << 16);
        p1 = (u32)d2 | ((u32)d3 << 16);
    } else {
        f32x4 w = *(const f32x4*)(W + ((size_t)((i * 4 + j) * 256 + e) << 8) + f);
        p0 = (u32)f2bf(w[0]) | ((u32)f2bf(w[1]) << 16);
        p1 = (u32)f2bf(w[2]) | ((u32)f2bf(w[3]) << 16);
    }
    u32x2 pr = {p0, p1};
    *(u32x2*)(Wimg + E) = pr;
}

// ---- Pre-swizzled B image, 128-col tiles (fallback path, R2-verified) ----
__global__ void prep_w128(const float* __restrict__ W, unsigned short* __restrict__ Wimg) {
    int t = blockIdx.x * blockDim.x + threadIdx.x;
    int E = t * 4;
    int tile = E >> 13;
    int pin = E & 8191;
    int col = pin >> 6;
    int r2e = pin & 63;
    int ct = tile >> 4;
    int j = (tile >> 2) & 3;
    int kk = tile & 3;
    int kl = r2e ^ ((col & 7) << 3);
    int c = ct * 128 + col;
    int i = c >> 8, e = c & 255;
    int f = kk * 64 + kl;
    u32 p0, p1;
    if (i == j) {
        p0 = 0u; p1 = 0u;
    } else {
        f32x4 w = *(const f32x4*)(W + ((size_t)((i * 4 + j) * 256 + e) << 8) + f);
        p0 = (u32)f2bf(w[0]) | ((u32)f2bf(w[1]) << 16);
        p1 = (u32)f2bf(w[2]) | ((u32)f2bf(w[3]) << 16);
    }
    u32x2 pr = {p0, p1};
    *(u32x2*)(Wimg + E) = pr;
}

// ---- Pre-swizzled A image (R4-verified): tile (j*256+rt)*4+kk = 32KB image of
// swizzled A LDS [256 rows][64 K]: p: row=p>>6, r2e=p&63, kl=r2e^((row&7)<<3).
__global__ void prep_x(const float* __restrict__ x, unsigned short* __restrict__ Ximg) {
    int t = blockIdx.x * blockDim.x + threadIdx.x;
    long long E = (long long)t * 4;
    int tile = (int)(E >> 14);
    int pin = (int)(E & 16383);
    int row = pin >> 6;
    int r2e = pin & 63;
    int kk = tile & 3;
    int rt = (tile >> 2) & 255;
    int j = tile >> 10;
    int kl = r2e ^ ((row & 7) << 3);
    int n = rt * 256 + row;
    int f = kk * 64 + kl;
    f32x4 v = *(const f32x4*)(x + ((size_t)j * NN + n) * DD + f);
    u32 p0 = (u32)f2bf(v[0]) | ((u32)f2bf(v[1]) << 16);
    u32 p1 = (u32)f2bf(v[2]) | ((u32)f2bf(v[3]) << 16);
    u32x2 pr = {p0, p1};
    *(u32x2*)(Ximg + E) = pr;
}

// bsum[i*256+e] = sum_{j != i} b[i,j,e]
__global__ void prep_b(const float* __restrict__ b, float* __restrict__ bsum) {
    int c = blockIdx.x * blockDim.x + threadIdx.x;
    if (c >= 1024) return;
    int i = c >> 8, e = c & 255;
    float s = 0.0f;
    #pragma unroll
    for (int j = 0; j < 4; ++j)
        if (j != i) s += b[((i * 4 + j) << 8) + e];
    bsum[c] = s;
}

// ---- Main GEMM: 256x256 tile, BK=64, 8 waves (2x4), K=1024 (identity diag).
// Phase-ahead register pipeline: each phase's MFMA consumes frags whose ds_reads
// were issued in the PREVIOUS phase (lgkm-wait excludes this phase's reads via
// counted lgkmcnt + in-order DS retire) -> LDS-read drain overlaps MFMA.
__global__ __launch_bounds__(512, 2) void fusion_gemm5(
    const unsigned short* __restrict__ Wimg, const unsigned short* __restrict__ Ximg,
    const float* __restrict__ bsum, float* __restrict__ out) {
    __shared__ __attribute__((aligned(16))) char lds[2][65536];  // [buf]{A 32K | B 32K}

    const int tid = threadIdx.x;
    const int bid = blockIdx.x;
    const int xcd = bid & 7;
    const int slot = bid >> 3;
    const int ct = slot & 3;            // col tile == output modality i
    const int rhi = slot >> 2;
    const int rtile = rhi * 8 + xcd;
    const int n0 = rtile * 256;
    const int col0 = ct * 256;

    const int lane = tid & 63;
    const int wid = tid >> 6;
    const int wm = wid & 1;             // row half (128 rows)
    const int wn = wid >> 1;            // col quarter (64 cols)

    f32x4 acc[8][4];
    #pragma unroll
    for (int a = 0; a < 8; ++a)
        #pragma unroll
        for (int b2 = 0; b2 < 4; ++b2)
            acc[a][b2] = (f32x4){0.f, 0.f, 0.f, 0.f};

    const char* WimgB = (const char*)Wimg;
    const char* XimgB = (const char*)Ximg;
    const u32 loff = (u32)(wid * 1024);
    const u32 goff = (u32)(wid * 1024 + lane * 16);

    // static register sets (all indices compile-time -> stay in VGPRs)
    s16x8 Aa[2][4], Ab[2][4];           // A0 / A1 frags [kh][fm]
    s16x8 By[2][2], Bx[2][2], Bz[2][2]; // B1 / B0-even / B0-odd frags [kh][fn]

#define STG(t_, q_, D_)                                                               \
    {                                                                                 \
        int j_ = (t_) >> 2;                                                           \
        int kk_ = (t_) & 3;                                                           \
        const char* as_ = XimgB + (((size_t)((j_ * 256 + rtile) * 4 + kk_)) << 15)    \
                          + (q_) * 8192 + goff;                                       \
        gl2lds16(as_, (D_) + (q_) * 8192 + loff);                                     \
        const char* bs_ = WimgB + (((size_t)((ct * 4 + j_) * 4 + kk_)) << 15)         \
                          + (q_) * 8192 + goff;                                       \
        gl2lds16(bs_, (D_) + 32768 + (q_) * 8192 + loff);                             \
    }

#define RD_A(BUF_, mh_, SET_)                                                         \
    _Pragma("unroll")                                                                 \
    for (int kh = 0; kh < 2; ++kh) {                                                  \
        _Pragma("unroll")                                                             \
        for (int fm = 0; fm < 4; ++fm) {                                              \
            int r_ = wm * 128 + ((mh_) * 4 + fm) * 16 + (lane & 15);                  \
            u32 o_ = (u32)(r_ * 128 + kh * 64 + (lane >> 4) * 16);                    \
            o_ ^= (u32)((r_ & 7) << 4);                                               \
            SET_[kh][fm] = *(const s16x8*)((BUF_) + o_);                              \
        }                                                                             \
    }

#define RD_B(BUF_, nh_, SET_)                                                         \
    _Pragma("unroll")                                                                 \
    for (int kh = 0; kh < 2; ++kh) {                                                  \
        _Pragma("unroll")                                                             \
        for (int fn = 0; fn < 2; ++fn) {                                              \
            int c_ = wn * 64 + ((nh_) * 2 + fn) * 16 + (lane & 15);                   \
            u32 o_ = (u32)(c_ * 128 + kh * 64 + (lane >> 4) * 16);                    \
            o_ ^= (u32)((c_ & 7) << 4);                                               \
            SET_[kh][fn] = *(const s16x8*)((BUF_) + 32768 + o_);                      \
        }                                                                             \
    }

#define MM(AS_, BS_, mh_, nh_)                                                        \
    _Pragma("unroll")                                                                 \
    for (int kh = 0; kh < 2; ++kh) {                                                  \
        _Pragma("unroll")                                                             \
        for (int fm = 0; fm < 4; ++fm) {                                              \
            _Pragma("unroll")                                                         \
            for (int fn = 0; fn < 2; ++fn) {                                          \
                acc[(mh_) * 4 + fm][(nh_) * 2 + fn] =                                 \
                    __builtin_amdgcn_mfma_f32_16x16x32_bf16(                          \
                        AS_[kh][fm], BS_[kh][fn],                                     \
                        acc[(mh_) * 4 + fm][(nh_) * 2 + fn], 0, 0, 0);                \
            }                                                                         \
        }                                                                             \
    }

#define SB __builtin_amdgcn_sched_barrier(0)
#define BAR __builtin_amdgcn_s_barrier()
#define LGKM(n_) asm volatile("s_waitcnt lgkmcnt(" #n_ ")" ::: "memory")
#define VM0 asm volatile("s_waitcnt vmcnt(0)" ::: "memory")
#define PHASE_MFMA(AS_, BS_, mh_, nh_, LG_)                                           \
    SB; BAR; SB; LGKM(LG_); SB;                                                       \
    __builtin_amdgcn_s_setprio(1);                                                    \
    MM(AS_, BS_, mh_, nh_);                                                           \
    __builtin_amdgcn_s_setprio(0);                                                    \
    SB; BAR;

    char* Ebuf = lds[0];
    char* Obuf = lds[1];

    // ---- prologue: stage tile 0 -> E, publish, preload Aa(A0), Bx(B0) ----
    STG(0, 0, Ebuf); STG(0, 1, Ebuf); STG(0, 2, Ebuf); STG(0, 3, Ebuf);
    VM0;
    BAR; SB;
    RD_A(Ebuf, 0, Aa);
    RD_B(Ebuf, 0, Bx);

    #pragma unroll 1
    for (int it = 0; it < 8; ++it) {
        const int te = 2 * it;
        const bool nl = (it < 7);

        // ======== even tile (reads E, stages tile te+1 -> O) ========
        // P0: MFMA A0*B0 (Aa,Bx loaded prev-P3/prologue); issue B1 reads; stage q0-2
        RD_B(Ebuf, 1, By);
        STG(te + 1, 0, Obuf); STG(te + 1, 1, Obuf); STG(te + 1, 2, Obuf);
        PHASE_MFMA(Aa, Bx, 0, 0, 4);
        // P1: MFMA A0*B1; issue A1 reads; stage q3
        RD_A(Ebuf, 1, Ab);
        STG(te + 1, 3, Obuf);
        PHASE_MFMA(Aa, By, 0, 1, 8);
        // P2: MFMA A1*B1; no reads; drain DMA (issued >=1 phase ago) + publish O
        VM0;
        PHASE_MFMA(Ab, By, 1, 1, 0);
        // P3: MFMA A1*B0; issue next-tile A0,B0 reads from O (published)
        RD_A(Obuf, 0, Aa);
        RD_B(Obuf, 0, Bz);
        PHASE_MFMA(Ab, Bx, 1, 0, 12);

        // ======== odd tile (reads O, stages tile te+2 -> E) ========
        // P0: MFMA A0*B0 (Aa,Bz); issue B1 reads; stage q0-2 (E-reads drained @P2e)
        RD_B(Obuf, 1, By);
        if (nl) { STG(te + 2, 0, Ebuf); STG(te + 2, 1, Ebuf); STG(te + 2, 2, Ebuf); }
        PHASE_MFMA(Aa, Bz, 0, 0, 4);
        // P1: MFMA A0*B1; issue A1 reads; stage q3
        RD_A(Obuf, 1, Ab);
        if (nl) STG(te + 2, 3, Ebuf);
        PHASE_MFMA(Aa, By, 0, 1, 8);
        // P2: MFMA A1*B1; drain DMA + publish E
        VM0;
        PHASE_MFMA(Ab, By, 1, 1, 0);
        // P3: MFMA A1*B0; issue next-tile reads from E
        if (nl) {
            RD_A(Ebuf, 0, Aa);
            RD_B(Ebuf, 0, Bx);
            PHASE_MFMA(Ab, Bz, 1, 0, 12);
        } else {
            PHASE_MFMA(Ab, Bz, 1, 0, 0);
        }
    }

#undef STG
#undef RD_A
#undef RD_B
#undef MM
#undef SB
#undef BAR
#undef LGKM
#undef VM0
#undef PHASE_MFMA

    // ---- epilogue: out = acc + bsum (residual folded via identity diagonal) ----
    const int r0 = (lane >> 4) * 4;
    const int cl = lane & 15;
    #pragma unroll
    for (int mf = 0; mf < 8; ++mf) {
        #pragma unroll
        for (int nf = 0; nf < 4; ++nf) {
            int col_l = wn * 64 + nf * 16 + cl;
            float bs = bsum[col0 + col_l];
            #pragma unroll
            for (int r = 0; r < 4; ++r) {
                int n = n0 + wm * 128 + mf * 16 + r0 + r;
                size_t oidx = ((size_t)ct * NN + n) * DD + col_l;
                out[oidx] = acc[mf][nf][r] + bs;
            }
        }
    }
}

// ---- Fallback (R2-verified kernel) for small ws_size ----
__global__ __launch_bounds__(256, 2) void fusion_gemm_fb(
    const float* __restrict__ x, const unsigned short* __restrict__ Wimg,
    const float* __restrict__ bsum, float* __restrict__ out) {
    __shared__ __attribute__((aligned(16))) unsigned short Alds[128 * 64];
    __shared__ __attribute__((aligned(16))) unsigned short Blds[2][128 * 64];

    const int tid = threadIdx.x;
    const int bid = blockIdx.x;
    const int xcd = bid & 7;
    const int slot = bid >> 3;
    const int ct = slot & 7;
    const int rhi = slot >> 3;
    const int rtile = rhi * 8 + xcd;
    const int n0 = rtile * 128;
    const int col0 = ct * 128;
    const int i = ct >> 1;

    const int lane = tid & 63;
    const int wid = tid >> 6;
    const int wm = wid >> 1;
    const int wn = wid & 1;

    f32x4 acc[4][4];
    #pragma unroll
    for (int a = 0; a < 4; ++a)
        #pragma unroll
        for (int b2 = 0; b2 < 4; ++b2)
            acc[a][b2] = (f32x4){0.f, 0.f, 0.f, 0.f};

    const int sr = tid >> 1;
    const int sh = tid & 1;
    char* Ab = (char*)Alds;
    const char* WimgB = (const char*)Wimg;

    f32x4 av[8];
    {
        int j0 = (i == 0) ? 1 : 0;
        const float* asrc = x + (size_t)j0 * ((size_t)NN * DD) + (size_t)(n0 + sr) * DD + sh * 32;
        #pragma unroll
        for (int q = 0; q < 8; ++q) av[q] = *(const f32x4*)(asrc + q * 4);
        const char* base = WimgB + (((size_t)(ct * 4 + j0) * 4 + 0) << 14) + wid * 1024 + lane * 16;
        char* lb = (char*)Blds[0] + wid * 1024;
        #pragma unroll
        for (int q = 0; q < 4; ++q) gl2lds16(base + q * 4096, lb + q * 4096);
    }

    for (int t = 0; t < 12; ++t) {
        __syncthreads();
        #pragma unroll
        for (int q = 0; q < 4; ++q) {
            f32x4 v0 = av[2 * q], v1 = av[2 * q + 1];
            u32x4 p;
            p[0] = (u32)f2bf(v0[0]) | ((u32)f2bf(v0[1]) << 16);
            p[1] = (u32)f2bf(v0[2]) | ((u32)f2bf(v0[3]) << 16);
            p[2] = (u32)f2bf(v1[0]) | ((u32)f2bf(v1[1]) << 16);
            p[3] = (u32)f2bf(v1[2]) | ((u32)f2bf(v1[3]) << 16);
            u32 o = (u32)(sr * 128 + sh * 64 + q * 16);
            o ^= (u32)((sr & 7) << 4);
            *(u32x4*)(Ab + o) = p;
        }
        __syncthreads();

        if (t < 11) {
            int tn = t + 1;
            int jjn = tn >> 2;
            int jn = jjn + (jjn >= i);
            int kkn = tn & 3;
            const char* base = WimgB + (((size_t)(ct * 4 + jn) * 4 + kkn) << 14) + wid * 1024 + lane * 16;
            char* lb = (char*)Blds[tn & 1] + wid * 1024;
            #pragma unroll
            for (int q = 0; q < 4; ++q) gl2lds16(base + q * 4096, lb + q * 4096);
            const float* asrc = x + (size_t)jn * ((size_t)NN * DD) + (size_t)(n0 + sr) * DD + kkn * 64 + sh * 32;
            #pragma unroll
            for (int q = 0; q < 8; ++q) av[q] = *(const f32x4*)(asrc + q * 4);
        }

        const char* Bb = (const char*)Blds[t & 1];
        #pragma unroll
        for (int kh = 0; kh < 2; ++kh) {
            s16x8 af[4], bfr[4];
            #pragma unroll
            for (int fm = 0; fm < 4; ++fm) {
                int row = wm * 64 + fm * 16 + (lane & 15);
                u32 o = (u32)(row * 128 + kh * 64 + (lane >> 4) * 16);
                o ^= (u32)((row & 7) << 4);
                af[fm] = *(const s16x8*)(Ab + o);
            }
            #pragma unroll
            for (int fn = 0; fn < 4; ++fn) {
                int col = wn * 64 + fn * 16 + (lane & 15);
                u32 o = (u32)(col * 128 + kh * 64 + (lane >> 4) * 16);
                o ^= (u32)((col & 7) << 4);
                bfr[fn] = *(const s16x8*)(Bb + o);
            }
            #pragma unroll
            for (int fm = 0; fm < 4; ++fm)
                #pragma unroll
                for (int fn = 0; fn < 4; ++fn)
                    acc[fm][fn] = __builtin_amdgcn_mfma_f32_16x16x32_bf16(
                        af[fm], bfr[fn], acc[fm][fn], 0, 0, 0);
        }
    }

    const int r0 = (lane >> 4) * 4;
    const int cl = lane & 15;
    #pragma unroll
    for (int fm = 0; fm < 4; ++fm) {
        #pragma unroll
        for (int fn = 0; fn < 4; ++fn) {
            int col_l = wn * 64 + fn * 16 + cl;
            int cglob = col0 + col_l;
            float bs = bsum[cglob];
            int e = cglob & 255;
            #pragma unroll
            for (int r = 0; r < 4; ++r) {
                int row_l = wm * 64 + fm * 16 + r0 + r;
                int n = n0 + row_l;
                size_t oidx = ((size_t)i * NN + n) * DD + e;
                out[oidx] = acc[fm][fn][r] + x[oidx] + bs;
            }
        }
    }
}

extern "C" void kernel_launch(void* const* d_in, const int* in_sizes, int n_in,
                              void* d_out, int out_size, void* d_ws, size_t ws_size,
                              hipStream_t stream) {
    const float* x = (const float*)d_in[0];
    const float* W = (const float*)d_in[1];
    const float* b = (const float*)d_in[2];
    float* out = (float*)d_out;

    unsigned short* Wimg = (unsigned short*)d_ws;                      // 8 MB (256-col) / 2 MB (fb)
    float* bsum = (float*)((char*)d_ws + ((size_t)8 << 20));           // 4 KB
    const size_t ximg_off = (size_t)9 << 20;
    const size_t need = ximg_off + ((size_t)128 << 20);                // 137 MB

    if (ws_size >= need) {
        float* bsum2 = (float*)((char*)d_ws + ((size_t)8 << 20));
        unsigned short* Ximg = (unsigned short*)((char*)d_ws + ximg_off);
        hipLaunchKernelGGL(prep_b, dim3(4), dim3(256), 0, stream, b, bsum2);
        hipLaunchKernelGGL(prep_w256, dim3(1024), dim3(256), 0, stream, W, Wimg);
        hipLaunchKernelGGL(prep_x, dim3(65536), dim3(256), 0, stream, x, Ximg);
        hipLaunchKernelGGL(fusion_gemm5, dim3(1024), dim3(512), 0, stream, Wimg, Ximg, bsum2, out);
    } else {
        float* bsum2 = (float*)((char*)d_ws + ((size_t)2 << 20));
        hipLaunchKernelGGL(prep_b, dim3(4), dim3(256), 0, stream, b, bsum2);
        hipLaunchKernelGGL(prep_w128, dim3(1024), dim3(256), 0, stream, W, Wimg);
        hipLaunchKernelGGL(fusion_gemm_fb, dim3(4096), dim3(256), 0, stream, x, Wimg, bsum2, out);
    }
}

// Round 7
// 257.663 us; speedup vs baseline: 3.6823x; 3.6823x over previous
//
#include <hip/hip_runtime.h>
#include <hip/hip_bf16.h>
#include <stdint.h>

#define NN 65536
#define DD 256

typedef uint32_t u32;
typedef __attribute__((ext_vector_type(4))) float f32x4;
typedef __attribute__((ext_vector_type(4))) u32 u32x4;
typedef __attribute__((ext_vector_type(2))) u32 u32x2;
typedef __attribute__((ext_vector_type(8))) short s16x8;

__device__ inline unsigned short f2bf(float f) {
    union { float f; u32 u; } v; v.f = f;
    u32 u = v.u;
    return (unsigned short)((u + 0x7fffu + ((u >> 16) & 1u)) >> 16);
}

__device__ inline void gl2lds16(const void* g, void* s) {
    __builtin_amdgcn_global_load_lds(
        (const __attribute__((address_space(1))) void*)g,
        (__attribute__((address_space(3))) void*)s, 16, 0, 0);
}

// ---- Pre-swizzled B image, 256-col tiles (R5-verified). Tile (ct,j,kk) = 32KB
// byte image of swizzled B LDS [256 cols][64 K] bf16; i==j block = bf16 identity.
__global__ void prep_w256(const float* __restrict__ W, unsigned short* __restrict__ Wimg) {
    int t = blockIdx.x * blockDim.x + threadIdx.x;
    int E = t * 4;
    int tile = E >> 14;
    int pin = E & 16383;
    int col = pin >> 6;
    int r2e = pin & 63;
    int ct = tile >> 4;
    int j = (tile >> 2) & 3;
    int kk = tile & 3;
    int kl = r2e ^ ((col & 7) << 3);
    int i = ct;
    int e = col;
    int f = kk * 64 + kl;
    u32 p0, p1;
    if (i == j) {
        unsigned short d0 = (e == f + 0) ? 0x3F80 : 0;
        unsigned short d1 = (e == f + 1) ? 0x3F80 : 0;
        unsigned short d2 = (e == f + 2) ? 0x3F80 : 0;
        unsigned short d3 = (e == f + 3) ? 0x3F80 : 0;
        p0 = (u32)d0 | ((u32)d1 << 16);
        p1 = (u32)d2 | ((u32)d3 << 16);
    } else {
        f32x4 w = *(const f32x4*)(W + ((size_t)((i * 4 + j) * 256 + e) << 8) + f);
        p0 = (u32)f2bf(w[0]) | ((u32)f2bf(w[1]) << 16);
        p1 = (u32)f2bf(w[2]) | ((u32)f2bf(w[3]) << 16);
    }
    u32x2 pr = {p0, p1};
    *(u32x2*)(Wimg + E) = pr;
}

// ---- Pre-swizzled B image, 128-col tiles (fallback path, R2-verified) ----
__global__ void prep_w128(const float* __restrict__ W, unsigned short* __restrict__ Wimg) {
    int t = blockIdx.x * blockDim.x + threadIdx.x;
    int E = t * 4;
    int tile = E >> 13;
    int pin = E & 8191;
    int col = pin >> 6;
    int r2e = pin & 63;
    int ct = tile >> 4;
    int j = (tile >> 2) & 3;
    int kk = tile & 3;
    int kl = r2e ^ ((col & 7) << 3);
    int c = ct * 128 + col;
    int i = c >> 8, e = c & 255;
    int f = kk * 64 + kl;
    u32 p0, p1;
    if (i == j) {
        p0 = 0u; p1 = 0u;
    } else {
        f32x4 w = *(const f32x4*)(W + ((size_t)((i * 4 + j) * 256 + e) << 8) + f);
        p0 = (u32)f2bf(w[0]) | ((u32)f2bf(w[1]) << 16);
        p1 = (u32)f2bf(w[2]) | ((u32)f2bf(w[3]) << 16);
    }
    u32x2 pr = {p0, p1};
    *(u32x2*)(Wimg + E) = pr;
}

// ---- Pre-swizzled A image (R4-verified): tile (j*256+rt)*4+kk = 32KB image of
// swizzled A LDS [256 rows][64 K]: p: row=p>>6, r2e=p&63, kl=r2e^((row&7)<<3).
__global__ void prep_x(const float* __restrict__ x, unsigned short* __restrict__ Ximg) {
    int t = blockIdx.x * blockDim.x + threadIdx.x;
    long long E = (long long)t * 4;
    int tile = (int)(E >> 14);
    int pin = (int)(E & 16383);
    int row = pin >> 6;
    int r2e = pin & 63;
    int kk = tile & 3;
    int rt = (tile >> 2) & 255;
    int j = tile >> 10;
    int kl = r2e ^ ((row & 7) << 3);
    int n = rt * 256 + row;
    int f = kk * 64 + kl;
    f32x4 v = *(const f32x4*)(x + ((size_t)j * NN + n) * DD + f);
    u32 p0 = (u32)f2bf(v[0]) | ((u32)f2bf(v[1]) << 16);
    u32 p1 = (u32)f2bf(v[2]) | ((u32)f2bf(v[3]) << 16);
    u32x2 pr = {p0, p1};
    *(u32x2*)(Ximg + E) = pr;
}

// bsum[i*256+e] = sum_{j != i} b[i,j,e]
__global__ void prep_b(const float* __restrict__ b, float* __restrict__ bsum) {
    int c = blockIdx.x * blockDim.x + threadIdx.x;
    if (c >= 1024) return;
    int i = c >> 8, e = c & 255;
    float s = 0.0f;
    #pragma unroll
    for (int j = 0; j < 4; ++j)
        if (j != i) s += b[((i * 4 + j) << 8) + e];
    bsum[c] = s;
}

// ---- Main GEMM: 256x256 tile, BK=64, 8 waves (2x4), K=1024 (identity diag).
// ONE barrier per K-tile (publish point), full-tile register fragments, staging
// issued at tile top; all ds_read<->MFMA interleave and counted lgkm waits left
// to the compiler (it emits fine-grained counted waits).
__global__ __launch_bounds__(512, 2) void fusion_gemm6(
    const unsigned short* __restrict__ Wimg, const unsigned short* __restrict__ Ximg,
    const float* __restrict__ bsum, float* __restrict__ out) {
    __shared__ __attribute__((aligned(16))) char lds[2][65536];  // [buf]{A 32K | B 32K}

    const int tid = threadIdx.x;
    const int bid = blockIdx.x;
    const int xcd = bid & 7;
    const int slot = bid >> 3;
    const int ct = slot & 3;            // col tile == output modality i
    const int rhi = slot >> 2;
    const int rtile = rhi * 8 + xcd;
    const int n0 = rtile * 256;
    const int col0 = ct * 256;

    const int lane = tid & 63;
    const int wid = tid >> 6;
    const int wm = wid & 1;             // row half (128 rows)
    const int wn = wid >> 1;            // col quarter (64 cols)

    f32x4 acc[8][4];
    #pragma unroll
    for (int a = 0; a < 8; ++a)
        #pragma unroll
        for (int b2 = 0; b2 < 4; ++b2)
            acc[a][b2] = (f32x4){0.f, 0.f, 0.f, 0.f};

    const char* WimgB = (const char*)Wimg;
    const char* XimgB = (const char*)Ximg;
    const u32 loff = (u32)(wid * 1024);
    const u32 goff = (u32)(wid * 1024 + lane * 16);

    // full-tile fragment registers (96 VGPR) — static indices only (rule #20)
    s16x8 fA0[2][4], fA1[2][4];   // A rows [wm*128 .. +64) / [+64 .. +128)
    s16x8 fB0[2][2], fB1[2][2];   // B cols [wn*64 .. +32) / [+32 .. +64)

#define STAGE_TILE(t_, D_)                                                            \
    {                                                                                 \
        int j_ = (t_) >> 2;                                                           \
        int kk_ = (t_) & 3;                                                           \
        const char* as_ = XimgB + (((size_t)((j_ * 256 + rtile) * 4 + kk_)) << 15) + goff; \
        const char* bs_ = WimgB + (((size_t)((ct * 4 + j_) * 4 + kk_)) << 15) + goff; \
        _Pragma("unroll")                                                             \
        for (int q = 0; q < 4; ++q) {                                                 \
            gl2lds16(as_ + q * 8192, (D_) + q * 8192 + loff);                         \
            gl2lds16(bs_ + q * 8192, (D_) + 32768 + q * 8192 + loff);                 \
        }                                                                             \
    }

#define RD_A(BUF_, mh_, SET_)                                                         \
    _Pragma("unroll")                                                                 \
    for (int kh = 0; kh < 2; ++kh) {                                                  \
        _Pragma("unroll")                                                             \
        for (int fm = 0; fm < 4; ++fm) {                                              \
            int r_ = wm * 128 + ((mh_) * 4 + fm) * 16 + (lane & 15);                  \
            u32 o_ = (u32)(r_ * 128 + kh * 64 + (lane >> 4) * 16);                    \
            o_ ^= (u32)((r_ & 7) << 4);                                               \
            SET_[kh][fm] = *(const s16x8*)((BUF_) + o_);                              \
        }                                                                             \
    }

#define RD_B(BUF_, nh_, SET_)                                                         \
    _Pragma("unroll")                                                                 \
    for (int kh = 0; kh < 2; ++kh) {                                                  \
        _Pragma("unroll")                                                             \
        for (int fn = 0; fn < 2; ++fn) {                                              \
            int c_ = wn * 64 + ((nh_) * 2 + fn) * 16 + (lane & 15);                   \
            u32 o_ = (u32)(c_ * 128 + kh * 64 + (lane >> 4) * 16);                    \
            o_ ^= (u32)((c_ & 7) << 4);                                               \
            SET_[kh][fn] = *(const s16x8*)((BUF_) + 32768 + o_);                      \
        }                                                                             \
    }

#define MM(AS_, BS_, mh_, nh_)                                                        \
    _Pragma("unroll")                                                                 \
    for (int kh = 0; kh < 2; ++kh) {                                                  \
        _Pragma("unroll")                                                             \
        for (int fm = 0; fm < 4; ++fm) {                                              \
            _Pragma("unroll")                                                         \
            for (int fn = 0; fn < 2; ++fn) {                                          \
                acc[(mh_) * 4 + fm][(nh_) * 2 + fn] =                                 \
                    __builtin_amdgcn_mfma_f32_16x16x32_bf16(                          \
                        AS_[kh][fm], BS_[kh][fn],                                     \
                        acc[(mh_) * 4 + fm][(nh_) * 2 + fn], 0, 0, 0);                \
            }                                                                         \
        }                                                                             \
    }

    // ---- prologue: stage tile 0 -> buf 0 ----
    STAGE_TILE(0, lds[0]);
    asm volatile("s_waitcnt vmcnt(0)" ::: "memory");
    __builtin_amdgcn_s_barrier();

    #pragma unroll 1
    for (int t = 0; t < 16; ++t) {
        const char* Bf = lds[t & 1];
        char* Of = lds[(t + 1) & 1];

        // issue next tile's staging first: HBM latency hides under this tile's work
        if (t < 15) STAGE_TILE(t + 1, Of);

        // fragment reads + MFMA clusters in source order; compiler interleaves
        // with counted lgkm waits (no manual drains, no intra-tile barriers).
        RD_A(Bf, 0, fA0);
        RD_B(Bf, 0, fB0);
        __builtin_amdgcn_s_setprio(1);
        MM(fA0, fB0, 0, 0);
        RD_B(Bf, 1, fB1);
        MM(fA0, fB1, 0, 1);
        RD_A(Bf, 1, fA1);
        MM(fA1, fB1, 1, 1);
        MM(fA1, fB0, 1, 0);
        __builtin_amdgcn_s_setprio(0);

        // publish: own staging landed; barrier covers (a) all waves' staging done
        // before next tile reads Of, (b) all waves' Bf reads retired (they fed
        // pre-barrier MFMAs) before Bf is restaged next iteration.
        asm volatile("s_waitcnt vmcnt(0)" ::: "memory");
        __builtin_amdgcn_s_barrier();
    }

#undef STAGE_TILE
#undef RD_A
#undef RD_B
#undef MM

    // ---- epilogue: out = acc + bsum (residual folded via identity diagonal) ----
    const int r0 = (lane >> 4) * 4;
    const int cl = lane & 15;
    #pragma unroll
    for (int mf = 0; mf < 8; ++mf) {
        #pragma unroll
        for (int nf = 0; nf < 4; ++nf) {
            int col_l = wn * 64 + nf * 16 + cl;
            float bs = bsum[col0 + col_l];
            #pragma unroll
            for (int r = 0; r < 4; ++r) {
                int n = n0 + wm * 128 + mf * 16 + r0 + r;
                size_t oidx = ((size_t)ct * NN + n) * DD + col_l;
                out[oidx] = acc[mf][nf][r] + bs;
            }
        }
    }
}

// ---- Fallback (R2-verified kernel) for small ws_size ----
__global__ __launch_bounds__(256, 2) void fusion_gemm_fb(
    const float* __restrict__ x, const unsigned short* __restrict__ Wimg,
    const float* __restrict__ bsum, float* __restrict__ out) {
    __shared__ __attribute__((aligned(16))) unsigned short Alds[128 * 64];
    __shared__ __attribute__((aligned(16))) unsigned short Blds[2][128 * 64];

    const int tid = threadIdx.x;
    const int bid = blockIdx.x;
    const int xcd = bid & 7;
    const int slot = bid >> 3;
    const int ct = slot & 7;
    const int rhi = slot >> 3;
    const int rtile = rhi * 8 + xcd;
    const int n0 = rtile * 128;
    const int col0 = ct * 128;
    const int i = ct >> 1;

    const int lane = tid & 63;
    const int wid = tid >> 6;
    const int wm = wid >> 1;
    const int wn = wid & 1;

    f32x4 acc[4][4];
    #pragma unroll
    for (int a = 0; a < 4; ++a)
        #pragma unroll
        for (int b2 = 0; b2 < 4; ++b2)
            acc[a][b2] = (f32x4){0.f, 0.f, 0.f, 0.f};

    const int sr = tid >> 1;
    const int sh = tid & 1;
    char* Ab = (char*)Alds;
    const char* WimgB = (const char*)Wimg;

    f32x4 av[8];
    {
        int j0 = (i == 0) ? 1 : 0;
        const float* asrc = x + (size_t)j0 * ((size_t)NN * DD) + (size_t)(n0 + sr) * DD + sh * 32;
        #pragma unroll
        for (int q = 0; q < 8; ++q) av[q] = *(const f32x4*)(asrc + q * 4);
        const char* base = WimgB + (((size_t)(ct * 4 + j0) * 4 + 0) << 14) + wid * 1024 + lane * 16;
        char* lb = (char*)Blds[0] + wid * 1024;
        #pragma unroll
        for (int q = 0; q < 4; ++q) gl2lds16(base + q * 4096, lb + q * 4096);
    }

    for (int t = 0; t < 12; ++t) {
        __syncthreads();
        #pragma unroll
        for (int q = 0; q < 4; ++q) {
            f32x4 v0 = av[2 * q], v1 = av[2 * q + 1];
            u32x4 p;
            p[0] = (u32)f2bf(v0[0]) | ((u32)f2bf(v0[1]) << 16);
            p[1] = (u32)f2bf(v0[2]) | ((u32)f2bf(v0[3]) << 16);
            p[2] = (u32)f2bf(v1[0]) | ((u32)f2bf(v1[1]) << 16);
            p[3] = (u32)f2bf(v1[2]) | ((u32)f2bf(v1[3]) << 16);
            u32 o = (u32)(sr * 128 + sh * 64 + q * 16);
            o ^= (u32)((sr & 7) << 4);
            *(u32x4*)(Ab + o) = p;
        }
        __syncthreads();

        if (t < 11) {
            int tn = t + 1;
            int jjn = tn >> 2;
            int jn = jjn + (jjn >= i);
            int kkn = tn & 3;
            const char* base = WimgB + (((size_t)(ct * 4 + jn) * 4 + kkn) << 14) + wid * 1024 + lane * 16;
            char* lb = (char*)Blds[tn & 1] + wid * 1024;
            #pragma unroll
            for (int q = 0; q < 4; ++q) gl2lds16(base + q * 4096, lb + q * 4096);
            const float* asrc = x + (size_t)jn * ((size_t)NN * DD) + (size_t)(n0 + sr) * DD + kkn * 64 + sh * 32;
            #pragma unroll
            for (int q = 0; q < 8; ++q) av[q] = *(const f32x4*)(asrc + q * 4);
        }

        const char* Bb = (const char*)Blds[t & 1];
        #pragma unroll
        for (int kh = 0; kh < 2; ++kh) {
            s16x8 af[4], bfr[4];
            #pragma unroll
            for (int fm = 0; fm < 4; ++fm) {
                int row = wm * 64 + fm * 16 + (lane & 15);
                u32 o = (u32)(row * 128 + kh * 64 + (lane >> 4) * 16);
                o ^= (u32)((row & 7) << 4);
                af[fm] = *(const s16x8*)(Ab + o);
            }
            #pragma unroll
            for (int fn = 0; fn < 4; ++fn) {
                int col = wn * 64 + fn * 16 + (lane & 15);
                u32 o = (u32)(col * 128 + kh * 64 + (lane >> 4) * 16);
                o ^= (u32)((col & 7) << 4);
                bfr[fn] = *(const s16x8*)(Bb + o);
            }
            #pragma unroll
            for (int fm = 0; fm < 4; ++fm)
                #pragma unroll
                for (int fn = 0; fn < 4; ++fn)
                    acc[fm][fn] = __builtin_amdgcn_mfma_f32_16x16x32_bf16(
                        af[fm], bfr[fn], acc[fm][fn], 0, 0, 0);
        }
    }

    const int r0 = (lane >> 4) * 4;
    const int cl = lane & 15;
    #pragma unroll
    for (int fm = 0; fm < 4; ++fm) {
        #pragma unroll
        for (int fn = 0; fn < 4; ++fn) {
            int col_l = wn * 64 + fn * 16 + cl;
            int cglob = col0 + col_l;
            float bs = bsum[cglob];
            int e = cglob & 255;
            #pragma unroll
            for (int r = 0; r < 4; ++r) {
                int row_l = wm * 64 + fm * 16 + r0 + r;
                int n = n0 + row_l;
                size_t oidx = ((size_t)i * NN + n) * DD + e;
                out[oidx] = acc[fm][fn][r] + x[oidx] + bs;
            }
        }
    }
}

extern "C" void kernel_launch(void* const* d_in, const int* in_sizes, int n_in,
                              void* d_out, int out_size, void* d_ws, size_t ws_size,
                              hipStream_t stream) {
    const float* x = (const float*)d_in[0];
    const float* W = (const float*)d_in[1];
    const float* b = (const float*)d_in[2];
    float* out = (float*)d_out;

    unsigned short* Wimg = (unsigned short*)d_ws;                      // 2 MB image (either path)
    float* bsum = (float*)((char*)d_ws + ((size_t)8 << 20));           // 4 KB
    const size_t ximg_off = (size_t)9 << 20;
    const size_t need = ximg_off + ((size_t)128 << 20);                // 137 MB

    if (ws_size >= need) {
        unsigned short* Ximg = (unsigned short*)((char*)d_ws + ximg_off);
        hipLaunchKernelGGL(prep_b, dim3(4), dim3(256), 0, stream, b, bsum);
        hipLaunchKernelGGL(prep_w256, dim3(1024), dim3(256), 0, stream, W, Wimg);
        hipLaunchKernelGGL(prep_x, dim3(65536), dim3(256), 0, stream, x, Ximg);
        hipLaunchKernelGGL(fusion_gemm6, dim3(1024), dim3(512), 0, stream, Wimg, Ximg, bsum, out);
    } else {
        float* bsum2 = (float*)((char*)d_ws + ((size_t)2 << 20));
        hipLaunchKernelGGL(prep_b, dim3(4), dim3(256), 0, stream, b, bsum2);
        hipLaunchKernelGGL(prep_w128, dim3(1024), dim3(256), 0, stream, W, Wimg);
        hipLaunchKernelGGL(fusion_gemm_fb, dim3(4096), dim3(256), 0, stream, x, Wimg, bsum2, out);
    }
}

// Round 8
// 257.475 us; speedup vs baseline: 3.6850x; 1.0007x over previous
//
#include <hip/hip_runtime.h>
#include <hip/hip_bf16.h>
#include <stdint.h>

#define NN 65536
#define DD 256

typedef uint32_t u32;
typedef __attribute__((ext_vector_type(4))) float f32x4;
typedef __attribute__((ext_vector_type(4))) u32 u32x4;
typedef __attribute__((ext_vector_type(2))) u32 u32x2;
typedef __attribute__((ext_vector_type(8))) short s16x8;

__device__ inline unsigned short f2bf(float f) {
    union { float f; u32 u; } v; v.f = f;
    u32 u = v.u;
    return (unsigned short)((u + 0x7fffu + ((u >> 16) & 1u)) >> 16);
}

__device__ inline void gl2lds16(const void* g, void* s) {
    __builtin_amdgcn_global_load_lds(
        (const __attribute__((address_space(1))) void*)g,
        (__attribute__((address_space(3))) void*)s, 16, 0, 0);
}

// ---- Pre-swizzled B image, 256-col tiles (R5-verified). Tile (ct,j,kk) = 32KB
// byte image of swizzled B LDS [256 cols][64 K] bf16; i==j block = bf16 identity.
__global__ void prep_w256(const float* __restrict__ W, unsigned short* __restrict__ Wimg) {
    int t = blockIdx.x * blockDim.x + threadIdx.x;
    int E = t * 4;
    int tile = E >> 14;
    int pin = E & 16383;
    int col = pin >> 6;
    int r2e = pin & 63;
    int ct = tile >> 4;
    int j = (tile >> 2) & 3;
    int kk = tile & 3;
    int kl = r2e ^ ((col & 7) << 3);
    int i = ct;
    int e = col;
    int f = kk * 64 + kl;
    u32 p0, p1;
    if (i == j) {
        unsigned short d0 = (e == f + 0) ? 0x3F80 : 0;
        unsigned short d1 = (e == f + 1) ? 0x3F80 : 0;
        unsigned short d2 = (e == f + 2) ? 0x3F80 : 0;
        unsigned short d3 = (e == f + 3) ? 0x3F80 : 0;
        p0 = (u32)d0 | ((u32)d1 << 16);
        p1 = (u32)d2 | ((u32)d3 << 16);
    } else {
        f32x4 w = *(const f32x4*)(W + ((size_t)((i * 4 + j) * 256 + e) << 8) + f);
        p0 = (u32)f2bf(w[0]) | ((u32)f2bf(w[1]) << 16);
        p1 = (u32)f2bf(w[2]) | ((u32)f2bf(w[3]) << 16);
    }
    u32x2 pr = {p0, p1};
    *(u32x2*)(Wimg + E) = pr;
}

// ---- Pre-swizzled B image, 128-col tiles (fallback path, R2-verified) ----
__global__ void prep_w128(const float* __restrict__ W, unsigned short* __restrict__ Wimg) {
    int t = blockIdx.x * blockDim.x + threadIdx.x;
    int E = t * 4;
    int tile = E >> 13;
    int pin = E & 8191;
    int col = pin >> 6;
    int r2e = pin & 63;
    int ct = tile >> 4;
    int j = (tile >> 2) & 3;
    int kk = tile & 3;
    int kl = r2e ^ ((col & 7) << 3);
    int c = ct * 128 + col;
    int i = c >> 8, e = c & 255;
    int f = kk * 64 + kl;
    u32 p0, p1;
    if (i == j) {
        p0 = 0u; p1 = 0u;
    } else {
        f32x4 w = *(const f32x4*)(W + ((size_t)((i * 4 + j) * 256 + e) << 8) + f);
        p0 = (u32)f2bf(w[0]) | ((u32)f2bf(w[1]) << 16);
        p1 = (u32)f2bf(w[2]) | ((u32)f2bf(w[3]) << 16);
    }
    u32x2 pr = {p0, p1};
    *(u32x2*)(Wimg + E) = pr;
}

// ---- Pre-swizzled A image (R4-verified): tile (j*256+rt)*4+kk = 32KB image of
// swizzled A LDS [256 rows][64 K]: p: row=p>>6, r2e=p&63, kl=r2e^((row&7)<<3).
__global__ void prep_x(const float* __restrict__ x, unsigned short* __restrict__ Ximg) {
    int t = blockIdx.x * blockDim.x + threadIdx.x;
    long long E = (long long)t * 4;
    int tile = (int)(E >> 14);
    int pin = (int)(E & 16383);
    int row = pin >> 6;
    int r2e = pin & 63;
    int kk = tile & 3;
    int rt = (tile >> 2) & 255;
    int j = tile >> 10;
    int kl = r2e ^ ((row & 7) << 3);
    int n = rt * 256 + row;
    int f = kk * 64 + kl;
    f32x4 v = *(const f32x4*)(x + ((size_t)j * NN + n) * DD + f);
    u32 p0 = (u32)f2bf(v[0]) | ((u32)f2bf(v[1]) << 16);
    u32 p1 = (u32)f2bf(v[2]) | ((u32)f2bf(v[3]) << 16);
    u32x2 pr = {p0, p1};
    *(u32x2*)(Ximg + E) = pr;
}

// bsum[i*256+e] = sum_{j != i} b[i,j,e]
__global__ void prep_b(const float* __restrict__ b, float* __restrict__ bsum) {
    int c = blockIdx.x * blockDim.x + threadIdx.x;
    if (c >= 1024) return;
    int i = c >> 8, e = c & 255;
    float s = 0.0f;
    #pragma unroll
    for (int j = 0; j < 4; ++j)
        if (j != i) s += b[((i * 4 + j) << 8) + e];
    bsum[c] = s;
}

// ---- Main GEMM: 256x256 tile, BK=64, 8 waves (2x4), K=1024 (identity diag).
// R7 structure (1 barrier/tile, full-tile reg frags) + T19 sched_group_barrier
// forcing ds_read/MFMA interleave: 12 gate reads, then {2 MFMA,1 read}x12, then
// 40 MFMA — remaining reads drain under the first MFMA clusters.
__global__ __launch_bounds__(512, 2) void fusion_gemm7(
    const unsigned short* __restrict__ Wimg, const unsigned short* __restrict__ Ximg,
    const float* __restrict__ bsum, float* __restrict__ out) {
    __shared__ __attribute__((aligned(16))) char lds[2][65536];  // [buf]{A 32K | B 32K}

    const int tid = threadIdx.x;
    const int bid = blockIdx.x;
    const int xcd = bid & 7;
    const int slot = bid >> 3;
    const int ct = slot & 3;            // col tile == output modality i
    const int rhi = slot >> 2;
    const int rtile = rhi * 8 + xcd;
    const int n0 = rtile * 256;
    const int col0 = ct * 256;

    const int lane = tid & 63;
    const int wid = tid >> 6;
    const int wm = wid & 1;             // row half (128 rows)
    const int wn = wid >> 1;            // col quarter (64 cols)

    f32x4 acc[8][4];
    #pragma unroll
    for (int a = 0; a < 8; ++a)
        #pragma unroll
        for (int b2 = 0; b2 < 4; ++b2)
            acc[a][b2] = (f32x4){0.f, 0.f, 0.f, 0.f};

    const char* WimgB = (const char*)Wimg;
    const char* XimgB = (const char*)Ximg;
    const u32 loff = (u32)(wid * 1024);
    const u32 goff = (u32)(wid * 1024 + lane * 16);

    // full-tile fragment registers — static indices only (rule #20)
    s16x8 fA0[2][4], fA1[2][4];   // A rows [wm*128 .. +64) / [+64 .. +128)
    s16x8 fB0[2][2], fB1[2][2];   // B cols [wn*64 .. +32) / [+32 .. +64)

#define STAGE_TILE(t_, D_)                                                            \
    {                                                                                 \
        int j_ = (t_) >> 2;                                                           \
        int kk_ = (t_) & 3;                                                           \
        const char* as_ = XimgB + (((size_t)((j_ * 256 + rtile) * 4 + kk_)) << 15) + goff; \
        const char* bs_ = WimgB + (((size_t)((ct * 4 + j_) * 4 + kk_)) << 15) + goff; \
        _Pragma("unroll")                                                             \
        for (int q = 0; q < 4; ++q) {                                                 \
            gl2lds16(as_ + q * 8192, (D_) + q * 8192 + loff);                         \
            gl2lds16(bs_ + q * 8192, (D_) + 32768 + q * 8192 + loff);                 \
        }                                                                             \
    }

#define RD_A(BUF_, mh_, SET_)                                                         \
    _Pragma("unroll")                                                                 \
    for (int kh = 0; kh < 2; ++kh) {                                                  \
        _Pragma("unroll")                                                             \
        for (int fm = 0; fm < 4; ++fm) {                                              \
            int r_ = wm * 128 + ((mh_) * 4 + fm) * 16 + (lane & 15);                  \
            u32 o_ = (u32)(r_ * 128 + kh * 64 + (lane >> 4) * 16);                    \
            o_ ^= (u32)((r_ & 7) << 4);                                               \
            SET_[kh][fm] = *(const s16x8*)((BUF_) + o_);                              \
        }                                                                             \
    }

#define RD_B(BUF_, nh_, SET_)                                                         \
    _Pragma("unroll")                                                                 \
    for (int kh = 0; kh < 2; ++kh) {                                                  \
        _Pragma("unroll")                                                             \
        for (int fn = 0; fn < 2; ++fn) {                                              \
            int c_ = wn * 64 + ((nh_) * 2 + fn) * 16 + (lane & 15);                   \
            u32 o_ = (u32)(c_ * 128 + kh * 64 + (lane >> 4) * 16);                    \
            o_ ^= (u32)((c_ & 7) << 4);                                               \
            SET_[kh][fn] = *(const s16x8*)((BUF_) + 32768 + o_);                      \
        }                                                                             \
    }

#define MM(AS_, BS_, mh_, nh_)                                                        \
    _Pragma("unroll")                                                                 \
    for (int kh = 0; kh < 2; ++kh) {                                                  \
        _Pragma("unroll")                                                             \
        for (int fm = 0; fm < 4; ++fm) {                                              \
            _Pragma("unroll")                                                         \
            for (int fn = 0; fn < 2; ++fn) {                                          \
                acc[(mh_) * 4 + fm][(nh_) * 2 + fn] =                                 \
                    __builtin_amdgcn_mfma_f32_16x16x32_bf16(                          \
                        AS_[kh][fm], BS_[kh][fn],                                     \
                        acc[(mh_) * 4 + fm][(nh_) * 2 + fn], 0, 0, 0);                \
            }                                                                         \
        }                                                                             \
    }

#define SGB(m_, n_) __builtin_amdgcn_sched_group_barrier((m_), (n_), 0)

    // ---- prologue: stage tile 0 -> buf 0 ----
    STAGE_TILE(0, lds[0]);
    asm volatile("s_waitcnt vmcnt(0)" ::: "memory");
    __builtin_amdgcn_s_barrier();

    #pragma unroll 1
    for (int t = 0; t < 16; ++t) {
        const char* Bf = lds[t & 1];
        char* Of = lds[(t + 1) & 1];

        // issue next tile's staging first: HBM latency hides under this tile's work
        if (t < 15) STAGE_TILE(t + 1, Of);

        __builtin_amdgcn_s_setprio(1);
        // source order: all reads, then all MFMA; SGB below forces the interleave.
        RD_A(Bf, 0, fA0);       // reads  1-8   (gate for c0)
        RD_B(Bf, 0, fB0);       // reads  9-12  (gate for c0)
        RD_B(Bf, 1, fB1);       // reads 13-16  (needed from MFMA #17)
        RD_A(Bf, 1, fA1);       // reads 17-24  (needed from MFMA #33)
        MM(fA0, fB0, 0, 0);     // MFMA  1-16
        MM(fA0, fB1, 0, 1);     // MFMA 17-32
        MM(fA1, fB1, 1, 1);     // MFMA 33-48
        MM(fA1, fB0, 1, 0);     // MFMA 49-64
        __builtin_amdgcn_s_setprio(0);

        // T19 emission pattern: 12 gate reads -> {2 MFMA, 1 read}x12 -> 40 MFMA.
        SGB(0x100, 12);                 // DS_READ x12
        #pragma unroll
        for (int g = 0; g < 12; ++g) {
            SGB(0x8, 2);                // MFMA x2
            SGB(0x100, 1);              // DS_READ x1
        }
        SGB(0x8, 40);                   // MFMA x40

        // publish: own staging landed; barrier covers cross-wave staging + WAR on Bf.
        asm volatile("s_waitcnt vmcnt(0)" ::: "memory");
        __builtin_amdgcn_s_barrier();
    }

#undef STAGE_TILE
#undef RD_A
#undef RD_B
#undef MM
#undef SGB

    // ---- epilogue: out = acc + bsum (residual folded via identity diagonal) ----
    const int r0 = (lane >> 4) * 4;
    const int cl = lane & 15;
    #pragma unroll
    for (int mf = 0; mf < 8; ++mf) {
        #pragma unroll
        for (int nf = 0; nf < 4; ++nf) {
            int col_l = wn * 64 + nf * 16 + cl;
            float bs = bsum[col0 + col_l];
            #pragma unroll
            for (int r = 0; r < 4; ++r) {
                int n = n0 + wm * 128 + mf * 16 + r0 + r;
                size_t oidx = ((size_t)ct * NN + n) * DD + col_l;
                out[oidx] = acc[mf][nf][r] + bs;
            }
        }
    }
}

// ---- Fallback (R2-verified kernel) for small ws_size ----
__global__ __launch_bounds__(256, 2) void fusion_gemm_fb(
    const float* __restrict__ x, const unsigned short* __restrict__ Wimg,
    const float* __restrict__ bsum, float* __restrict__ out) {
    __shared__ __attribute__((aligned(16))) unsigned short Alds[128 * 64];
    __shared__ __attribute__((aligned(16))) unsigned short Blds[2][128 * 64];

    const int tid = threadIdx.x;
    const int bid = blockIdx.x;
    const int xcd = bid & 7;
    const int slot = bid >> 3;
    const int ct = slot & 7;
    const int rhi = slot >> 3;
    const int rtile = rhi * 8 + xcd;
    const int n0 = rtile * 128;
    const int col0 = ct * 128;
    const int i = ct >> 1;

    const int lane = tid & 63;
    const int wid = tid >> 6;
    const int wm = wid >> 1;
    const int wn = wid & 1;

    f32x4 acc[4][4];
    #pragma unroll
    for (int a = 0; a < 4; ++a)
        #pragma unroll
        for (int b2 = 0; b2 < 4; ++b2)
            acc[a][b2] = (f32x4){0.f, 0.f, 0.f, 0.f};

    const int sr = tid >> 1;
    const int sh = tid & 1;
    char* Ab = (char*)Alds;
    const char* WimgB = (const char*)Wimg;

    f32x4 av[8];
    {
        int j0 = (i == 0) ? 1 : 0;
        const float* asrc = x + (size_t)j0 * ((size_t)NN * DD) + (size_t)(n0 + sr) * DD + sh * 32;
        #pragma unroll
        for (int q = 0; q < 8; ++q) av[q] = *(const f32x4*)(asrc + q * 4);
        const char* base = WimgB + (((size_t)(ct * 4 + j0) * 4 + 0) << 14) + wid * 1024 + lane * 16;
        char* lb = (char*)Blds[0] + wid * 1024;
        #pragma unroll
        for (int q = 0; q < 4; ++q) gl2lds16(base + q * 4096, lb + q * 4096);
    }

    for (int t = 0; t < 12; ++t) {
        __syncthreads();
        #pragma unroll
        for (int q = 0; q < 4; ++q) {
            f32x4 v0 = av[2 * q], v1 = av[2 * q + 1];
            u32x4 p;
            p[0] = (u32)f2bf(v0[0]) | ((u32)f2bf(v0[1]) << 16);
            p[1] = (u32)f2bf(v0[2]) | ((u32)f2bf(v0[3]) << 16);
            p[2] = (u32)f2bf(v1[0]) | ((u32)f2bf(v1[1]) << 16);
            p[3] = (u32)f2bf(v1[2]) | ((u32)f2bf(v1[3]) << 16);
            u32 o = (u32)(sr * 128 + sh * 64 + q * 16);
            o ^= (u32)((sr & 7) << 4);
            *(u32x4*)(Ab + o) = p;
        }
        __syncthreads();

        if (t < 11) {
            int tn = t + 1;
            int jjn = tn >> 2;
            int jn = jjn + (jjn >= i);
            int kkn = tn & 3;
            const char* base = WimgB + (((size_t)(ct * 4 + jn) * 4 + kkn) << 14) + wid * 1024 + lane * 16;
            char* lb = (char*)Blds[tn & 1] + wid * 1024;
            #pragma unroll
            for (int q = 0; q < 4; ++q) gl2lds16(base + q * 4096, lb + q * 4096);
            const float* asrc = x + (size_t)jn * ((size_t)NN * DD) + (size_t)(n0 + sr) * DD + kkn * 64 + sh * 32;
            #pragma unroll
            for (int q = 0; q < 8; ++q) av[q] = *(const f32x4*)(asrc + q * 4);
        }

        const char* Bb = (const char*)Blds[t & 1];
        #pragma unroll
        for (int kh = 0; kh < 2; ++kh) {
            s16x8 af[4], bfr[4];
            #pragma unroll
            for (int fm = 0; fm < 4; ++fm) {
                int row = wm * 64 + fm * 16 + (lane & 15);
                u32 o = (u32)(row * 128 + kh * 64 + (lane >> 4) * 16);
                o ^= (u32)((row & 7) << 4);
                af[fm] = *(const s16x8*)(Ab + o);
            }
            #pragma unroll
            for (int fn = 0; fn < 4; ++fn) {
                int col = wn * 64 + fn * 16 + (lane & 15);
                u32 o = (u32)(col * 128 + kh * 64 + (lane >> 4) * 16);
                o ^= (u32)((col & 7) << 4);
                bfr[fn] = *(const s16x8*)(Bb + o);
            }
            #pragma unroll
            for (int fm = 0; fm < 4; ++fm)
                #pragma unroll
                for (int fn = 0; fn < 4; ++fn)
                    acc[fm][fn] = __builtin_amdgcn_mfma_f32_16x16x32_bf16(
                        af[fm], bfr[fn], acc[fm][fn], 0, 0, 0);
        }
    }

    const int r0 = (lane >> 4) * 4;
    const int cl = lane & 15;
    #pragma unroll
    for (int fm = 0; fm < 4; ++fm) {
        #pragma unroll
        for (int fn = 0; fn < 4; ++fn) {
            int col_l = wn * 64 + fn * 16 + cl;
            int cglob = col0 + col_l;
            float bs = bsum[cglob];
            int e = cglob & 255;
            #pragma unroll
            for (int r = 0; r < 4; ++r) {
                int row_l = wm * 64 + fm * 16 + r0 + r;
                int n = n0 + row_l;
                size_t oidx = ((size_t)i * NN + n) * DD + e;
                out[oidx] = acc[fm][fn][r] + x[oidx] + bs;
            }
        }
    }
}

extern "C" void kernel_launch(void* const* d_in, const int* in_sizes, int n_in,
                              void* d_out, int out_size, void* d_ws, size_t ws_size,
                              hipStream_t stream) {
    const float* x = (const float*)d_in[0];
    const float* W = (const float*)d_in[1];
    const float* b = (const float*)d_in[2];
    float* out = (float*)d_out;

    unsigned short* Wimg = (unsigned short*)d_ws;                      // images at ws base
    float* bsum = (float*)((char*)d_ws + ((size_t)8 << 20));           // 4 KB
    const size_t ximg_off = (size_t)9 << 20;
    const size_t need = ximg_off + ((size_t)128 << 20);                // 137 MB

    if (ws_size >= need) {
        unsigned short* Ximg = (unsigned short*)((char*)d_ws + ximg_off);
        hipLaunchKernelGGL(prep_b, dim3(4), dim3(256), 0, stream, b, bsum);
        hipLaunchKernelGGL(prep_w256, dim3(1024), dim3(256), 0, stream, W, Wimg);
        hipLaunchKernelGGL(prep_x, dim3(65536), dim3(256), 0, stream, x, Ximg);
        hipLaunchKernelGGL(fusion_gemm7, dim3(1024), dim3(512), 0, stream, Wimg, Ximg, bsum, out);
    } else {
        float* bsum2 = (float*)((char*)d_ws + ((size_t)2 << 20));
        hipLaunchKernelGGL(prep_b, dim3(4), dim3(256), 0, stream, b, bsum2);
        hipLaunchKernelGGL(prep_w128, dim3(1024), dim3(256), 0, stream, W, Wimg);
        hipLaunchKernelGGL(fusion_gemm_fb, dim3(4096), dim3(256), 0, stream, x, Wimg, bsum2, out);
    }
}